// Round 19
// baseline (892.675 us; speedup 1.0000x reference)
//
#include <hip/hip_runtime.h>
#include <hip/hip_bf16.h>

// FP8Linear: out = Xq @ Wq^T + bias. Reference quantize (scale=1) == RNE
// conversion to OCP e4m3fn; x stored as e4m3(x); w stored as e4m3(w*2^6)
// with MFMA B-scale 2^-6 (e8m0 0x79) so all |w|>=2^-12 quantize EXACTLY.
// GEMM R19: maximize TLP (the only session-correlated lever; R18's
// conflict-free null proved the LDS port has slack). Per-wave output
// 32x64 -> acc[1][2]=32 AGPR -> ~85 unified regs -> 6 waves/SIMD ->
// 3 blocks/CU -> 24 waves/CU (vs 16 cap of all acc[2][2] configs).
// 128x128 tile, BK=64, 512 thr / 8 waves (4Mx2N), dbuf 2x16KB LDS,
// DMA prefetch one full tile ahead, ONE __syncthreads per tile,
// R17-hardware-verified zero-conflict 64B-row swizzle q(r)=(r^(r>>2))&3
// (both sides: pre-swizzled DMA source + swizzled read).
// mfma_scale_f32_32x32x64_f8f6f4; XCD-aware block swizzle.

typedef int i32x4 __attribute__((ext_vector_type(4)));
typedef int i32x8 __attribute__((ext_vector_type(8)));
typedef float f32x16 __attribute__((ext_vector_type(16)));

#define BM 128
#define BN 128
#define BK 64

// clip to +-448, scale (1 or 64), RNE-encode 8 f32 -> 8 e4m3 bytes.
__global__ __launch_bounds__(256) void quant8(
    const float4* __restrict__ in, int2* __restrict__ out, int n8, float scale) {
    int i = blockIdx.x * blockDim.x + threadIdx.x;
    if (i >= n8) return;
    float4 a = in[i * 2];
    float4 b = in[i * 2 + 1];
    float c0 = fminf(fmaxf(a.x, -448.f), 448.f) * scale;
    float c1 = fminf(fmaxf(a.y, -448.f), 448.f) * scale;
    float c2 = fminf(fmaxf(a.z, -448.f), 448.f) * scale;
    float c3 = fminf(fmaxf(a.w, -448.f), 448.f) * scale;
    float c4 = fminf(fmaxf(b.x, -448.f), 448.f) * scale;
    float c5 = fminf(fmaxf(b.y, -448.f), 448.f) * scale;
    float c6 = fminf(fmaxf(b.z, -448.f), 448.f) * scale;
    float c7 = fminf(fmaxf(b.w, -448.f), 448.f) * scale;
    int lo = __builtin_amdgcn_cvt_pk_fp8_f32(c0, c1, 0, false);
    lo = __builtin_amdgcn_cvt_pk_fp8_f32(c2, c3, lo, true);
    int hi = __builtin_amdgcn_cvt_pk_fp8_f32(c4, c5, 0, false);
    hi = __builtin_amdgcn_cvt_pk_fp8_f32(c6, c7, hi, true);
    out[i] = make_int2(lo, hi);
}

__device__ __forceinline__ void gload_lds16(const void* g, void* l) {
    __builtin_amdgcn_global_load_lds(
        (const __attribute__((address_space(1))) void*)g,
        (__attribute__((address_space(3))) void*)l,
        16, 0, 0);
}

// 64B-row tile, slot swizzle q(r) = (r ^ (r>>2)) & 3 (R17: zero conflicts).
// LDS[r][slot s] holds logical slot s ^ q(r). Lane reads 32B = logical
// slots {2*g2, 2*g2+1} of `row`.
__device__ __forceinline__ i32x8 frag64(const unsigned char* base, int row, int g2) {
    const int q = (row ^ (row >> 2)) & 3;
    const unsigned char* p = base + (row << 6);
    i32x4 lo = *(const i32x4*)(p + ((((g2 << 1))     ^ q) << 4));
    i32x4 hi = *(const i32x4*)(p + ((((g2 << 1) | 1) ^ q) << 4));
    i32x8 r;
    r[0] = lo[0]; r[1] = lo[1]; r[2] = lo[2]; r[3] = lo[3];
    r[4] = hi[0]; r[5] = hi[1]; r[6] = hi[2]; r[7] = hi[3];
    return r;
}

// A: Xq8 [M][K] e4m3, B: Wq8 [N][K] e4m3 (pre-scaled by 2^6), C: [M][N] f32
__global__ __launch_bounds__(512, 3) void gemm_fp8(
    const unsigned char* __restrict__ A, const unsigned char* __restrict__ B,
    const float* __restrict__ bias, float* __restrict__ C,
    int M, int N, int K) {
    // buf0: A [0,8K) B [8K,16K); buf1: A [16K,24K) B [24K,32K)
    __shared__ unsigned char lds[32768];

    const int tid = threadIdx.x;
    const int lane = tid & 63;
    const int wave = tid >> 6;   // 0..7
    const int wr = wave >> 1;    // 0..3 -> 32 A-rows each
    const int wc = wave & 1;     // 0..1 -> 64 B-cols each

    // XCD-aware bijective block swizzle (nwg % 8 == 0)
    const int nwg = gridDim.x;
    const int per = nwg >> 3;
    const int bid = blockIdx.x;
    const int wg = (bid & 7) * per + (bid >> 3);
    const int mtiles = M / BM;
    const int bm = wg % mtiles;
    const int bn = wg / mtiles;

    const int arow0 = bm * BM, bcol0 = bn * BN;
    const int NT = K / BK;  // 64

    const int rl = lane & 31;    // fragment row-within-32 (A row / B col)
    const int g2 = lane >> 5;    // k-half selector (32B each)

    const unsigned char* const Ag = A + (size_t)arow0 * K;
    const unsigned char* const Bg = B + (size_t)bcol0 * K;

    // staging: 8KB unit = 128 rows x 64B; 512 thr x 16B = 1 instr each.
    // thread t -> row t>>2, LDS slot t&3 (linear dest); source col carries
    // the inverse swizzle: logical slot = (t&3) ^ q(row).
    const int srow = tid >> 2;                          // 0..127
    const int sq = (srow ^ (srow >> 2)) & 3;
    const int ssrc = (((tid & 3) ^ sq) << 4);           // byte col in row
    const int sdst = tid * 16;

    auto stage = [&](unsigned char* Lp, int kt) {
        gload_lds16(Ag + (size_t)srow * K + kt + ssrc, Lp + sdst);         // A
        gload_lds16(Bg + (size_t)srow * K + kt + ssrc, Lp + 8192 + sdst);  // B
    };

    f32x16 acc[2] = {};

    // ---- prologue: tile 0 -> buf0
    stage(lds, 0);
    __syncthreads();  // implicit vmcnt(0): tile 0 landed

    for (int t = 0; t < NT; ++t) {
        const int cur = t & 1;
        const unsigned char* Ab = lds + cur * 16384;
        const unsigned char* Bb = Ab + 8192;
        unsigned char* Anx = lds + (cur ^ 1) * 16384;

        // issue next tile's DMAs first: full tile of latency cover
        if (t + 1 < NT) stage(Anx, (t + 1) * BK);

        i32x8 af  = frag64(Ab, wr * 32 + rl, g2);
        i32x8 bf0 = frag64(Bb, wc * 64 + rl, g2);
        i32x8 bf1 = frag64(Bb, wc * 64 + 32 + rl, g2);

        acc[0] = __builtin_amdgcn_mfma_scale_f32_32x32x64_f8f6f4(
            af, bf0, acc[0], 0, 0, 0, 0x7F7F7F7F, 0, 0x79797979);
        acc[1] = __builtin_amdgcn_mfma_scale_f32_32x32x64_f8f6f4(
            af, bf1, acc[1], 0, 0, 0, 0x7F7F7F7F, 0, 0x79797979);

        // one sync/tile: DMAs issued ~full tile ago have landed; publishes
        // the next buffer and protects the one just consumed.
        __syncthreads();
    }

    // epilogue: 32x32 C/D: col = lane&31, row = (reg&3)+8*(reg>>2)+4*(lane>>5)
#pragma unroll
    for (int n = 0; n < 2; ++n) {
        int col = bcol0 + wc * 64 + n * 32 + rl;
        float bv = bias[col];
        int rowb = arow0 + wr * 32 + g2 * 4;
#pragma unroll
        for (int reg = 0; reg < 16; ++reg) {
            int row = rowb + (reg & 3) + 8 * (reg >> 2);
            C[(size_t)row * N + col] = acc[n][reg] + bv;
        }
    }
}

extern "C" void kernel_launch(void* const* d_in, const int* in_sizes, int n_in,
                              void* d_out, int out_size, void* d_ws, size_t ws_size,
                              hipStream_t stream) {
    const float* x = (const float*)d_in[0];     // [M,K]
    const float* w = (const float*)d_in[1];     // [N,K]
    const float* bias = (const float*)d_in[2];  // [N]
    float* out = (float*)d_out;

    const int N = in_sizes[2];                 // 16384
    const int K = in_sizes[1] / N;             // 4096
    const int M = in_sizes[0] / K;             // 8192

    unsigned char* xq = (unsigned char*)d_ws;          // M*K = 33.5 MB
    unsigned char* wq = xq + (size_t)M * K;            // N*K = 67 MB

    int nx8 = M * K / 8;
    int nw8 = N * K / 8;
    quant8<<<(nx8 + 255) / 256, 256, 0, stream>>>(
        (const float4*)x, (int2*)xq, nx8, 1.0f);
    quant8<<<(nw8 + 255) / 256, 256, 0, stream>>>(
        (const float4*)w, (int2*)wq, nw8, 64.0f);

    int nwg = (M / BM) * (N / BN);  // 64*128 = 8192, %8==0
    gemm_fp8<<<nwg, 512, 0, stream>>>(
        xq, wq, bias, out, M, N, K);
}

// Round 20
// 792.517 us; speedup vs baseline: 1.1264x; 1.1264x over previous
//
#include <hip/hip_runtime.h>
#include <hip/hip_bf16.h>

// FP8Linear: out = Xq @ Wq^T + bias. Reference quantize (scale=1) == RNE
// conversion to OCP e4m3fn; x stored as e4m3(x); w stored as e4m3(w*2^6)
// with MFMA B-scale 2^-6 (e8m0 0x79) so all |w|>=2^-12 quantize EXACTLY.
// FINAL (R20) = R15's GEMM (best measured: GEMM 691us, total 794us) +
// merged single-launch quant. Session summary: 11 structures spanning
// conflicts 0..2e8, occupancy 21..68%, 1/2/3-deep buffering all land
// 690-850us GEMM -> this is the 2-barrier-loop structural ceiling at MX
// rate (97% of learn_hip m148's 1628 TF for this exact structure class).
// Counted-vmcnt/8-phase ports failed 4x on this toolchain (pre-drain,
// order-pinning, spills) - documented and closed.
// GEMM config: 128x256 tile, BK=128 (sw=(r&7)<<4 low-conflict swizzle),
// single 48KB LDS buffer, 8 waves (2Mx4N, 64x64 out, acc[2][2]=64 AGPR),
// 2 blocks/CU, stage->sync->compute->sync, wave-parity ks-stagger,
// mfma_scale_f32_32x32x64_f8f6f4, pre-swizzled DMA source, XCD swizzle.

typedef int i32x4 __attribute__((ext_vector_type(4)));
typedef int i32x8 __attribute__((ext_vector_type(8)));
typedef float f32x16 __attribute__((ext_vector_type(16)));

#define BM 128
#define BN 256
#define BK 128

// Merged quant: covers x (scale 1) then w (scale 64) in one launch.
// clip to +-448, scale, RNE-encode 8 f32 -> 8 e4m3 bytes.
__global__ __launch_bounds__(256) void quant8_both(
    const float4* __restrict__ xin, int2* __restrict__ xout, int nx8,
    const float4* __restrict__ win, int2* __restrict__ wout, int nw8) {
    int i = blockIdx.x * blockDim.x + threadIdx.x;
    const float4* in;
    int2* out;
    float scale;
    int j;
    if (i < nx8) {
        in = xin; out = xout; scale = 1.0f; j = i;
    } else {
        j = i - nx8;
        if (j >= nw8) return;
        in = win; out = wout; scale = 64.0f;
    }
    float4 a = in[j * 2];
    float4 b = in[j * 2 + 1];
    float c0 = fminf(fmaxf(a.x, -448.f), 448.f) * scale;
    float c1 = fminf(fmaxf(a.y, -448.f), 448.f) * scale;
    float c2 = fminf(fmaxf(a.z, -448.f), 448.f) * scale;
    float c3 = fminf(fmaxf(a.w, -448.f), 448.f) * scale;
    float c4 = fminf(fmaxf(b.x, -448.f), 448.f) * scale;
    float c5 = fminf(fmaxf(b.y, -448.f), 448.f) * scale;
    float c6 = fminf(fmaxf(b.z, -448.f), 448.f) * scale;
    float c7 = fminf(fmaxf(b.w, -448.f), 448.f) * scale;
    int lo = __builtin_amdgcn_cvt_pk_fp8_f32(c0, c1, 0, false);
    lo = __builtin_amdgcn_cvt_pk_fp8_f32(c2, c3, lo, true);
    int hi = __builtin_amdgcn_cvt_pk_fp8_f32(c4, c5, 0, false);
    hi = __builtin_amdgcn_cvt_pk_fp8_f32(c6, c7, hi, true);
    out[j] = make_int2(lo, hi);
}

__device__ __forceinline__ void gload_lds16(const void* g, void* l) {
    __builtin_amdgcn_global_load_lds(
        (const __attribute__((address_space(1))) void*)g,
        (__attribute__((address_space(3))) void*)l,
        16, 0, 0);
}

// 128B-row tiles. LDS[r][c] holds G[r][c ^ sw(r)], sw(r) = (r&7)<<4.
// Read one lane's 32-byte k-block (logical cols [c0, c0+32)) of `row`.
__device__ __forceinline__ i32x8 frag32(const unsigned char* base, int row, int c0) {
    const int sw = (row & 7) << 4;
    const unsigned char* p = base + row * 128;
    i32x4 lo = *(const i32x4*)(p + (c0 ^ sw));
    i32x4 hi = *(const i32x4*)(p + ((c0 + 16) ^ sw));
    i32x8 r;
    r[0] = lo[0]; r[1] = lo[1]; r[2] = lo[2]; r[3] = lo[3];
    r[4] = hi[0]; r[5] = hi[1]; r[6] = hi[2]; r[7] = hi[3];
    return r;
}

// A: Xq8 [M][K] e4m3, B: Wq8 [N][K] e4m3 (pre-scaled by 2^6), C: [M][N] f32
__global__ __launch_bounds__(512, 2) void gemm_fp8(
    const unsigned char* __restrict__ A, const unsigned char* __restrict__ B,
    const float* __restrict__ bias, float* __restrict__ C,
    int M, int N, int K) {
    // single buffer: A [0,16K) + B [16K,48K)
    __shared__ unsigned char lds[49152];
    unsigned char* const lA = lds;
    unsigned char* const lB = lds + 16384;

    const int tid = threadIdx.x;
    const int lane = tid & 63;
    const int wave = tid >> 6;
    const int wr = wave >> 2;   // 0..1 -> 64 A-rows each
    const int wc = wave & 3;    // 0..3 -> 64 B-cols each
    const int ko = wave & 1;    // ks-stagger parity

    // XCD-aware bijective block swizzle (nwg % 8 == 0)
    const int nwg = gridDim.x;
    const int per = nwg >> 3;
    const int bid = blockIdx.x;
    const int wg = (bid & 7) * per + (bid >> 3);
    const int mtiles = M / BM;
    const int bm = wg % mtiles;
    const int bn = wg / mtiles;

    const int arow0 = bm * BM, bcol0 = bn * BN;
    const int NT = K / BK;  // 32

    const int rl = lane & 31;    // fragment row-within-32 (A row / B col)
    const int g2 = lane >> 5;    // k-half selector within 64-byte mfma k-range

    const unsigned char* const Ag = A + (size_t)arow0 * K;
    const unsigned char* const Bg = B + (size_t)bcol0 * K;

    // staging: 512 threads. A (16KB): 2 chunks of 64 rows; B (32KB): 4 chunks.
    // thread t: row-in-chunk = t>>3, logical col = (t&7)*16, dst linear,
    // src pre-swizzled (both-sides rule).
    const int srow = tid >> 3;                       // 0..63
    const int ssrc_col = ((tid & 7) * 16) ^ (((tid >> 3) & 7) << 4);
    const int sdst = tid * 16;

    auto stage = [&](int kt) {
#pragma unroll
        for (int c = 0; c < 2; ++c)
            gload_lds16(Ag + (size_t)(c * 64 + srow) * K + kt + ssrc_col,
                        lA + c * 8192 + sdst);
#pragma unroll
        for (int c = 0; c < 4; ++c)
            gload_lds16(Bg + (size_t)(c * 64 + srow) * K + kt + ssrc_col,
                        lB + c * 8192 + sdst);
    };

    f32x16 acc[2][2] = {};

    for (int t = 0; t < NT; ++t) {
        stage(t * BK);
        __syncthreads();  // implicit vmcnt(0): tile landed, visible to all

#pragma unroll
        for (int s = 0; s < 2; ++s) {
            const int ks = s ^ ko;  // odd waves run ks=1 first (stagger)
            const int c0 = ks * 64 + g2 * 32;
            i32x8 af0 = frag32(lA, wr * 64 + rl, c0);
            i32x8 af1 = frag32(lA, wr * 64 + 32 + rl, c0);
            i32x8 bf0 = frag32(lB, wc * 64 + rl, c0);
            i32x8 bf1 = frag32(lB, wc * 64 + 32 + rl, c0);

            acc[0][0] = __builtin_amdgcn_mfma_scale_f32_32x32x64_f8f6f4(
                af0, bf0, acc[0][0], 0, 0, 0, 0x7F7F7F7F, 0, 0x79797979);
            acc[0][1] = __builtin_amdgcn_mfma_scale_f32_32x32x64_f8f6f4(
                af0, bf1, acc[0][1], 0, 0, 0, 0x7F7F7F7F, 0, 0x79797979);
            acc[1][0] = __builtin_amdgcn_mfma_scale_f32_32x32x64_f8f6f4(
                af1, bf0, acc[1][0], 0, 0, 0, 0x7F7F7F7F, 0, 0x79797979);
            acc[1][1] = __builtin_amdgcn_mfma_scale_f32_32x32x64_f8f6f4(
                af1, bf1, acc[1][1], 0, 0, 0, 0x7F7F7F7F, 0, 0x79797979);
        }

        __syncthreads();  // protect buffer before next tile's DMA
    }

    // epilogue: 32x32 C/D: col = lane&31, row = (reg&3)+8*(reg>>2)+4*(lane>>5)
#pragma unroll
    for (int n = 0; n < 2; ++n) {
        int col = bcol0 + wc * 64 + n * 32 + rl;
        float bv = bias[col];
#pragma unroll
        for (int m = 0; m < 2; ++m) {
            int rowb = arow0 + wr * 64 + m * 32 + g2 * 4;
#pragma unroll
            for (int reg = 0; reg < 16; ++reg) {
                int row = rowb + (reg & 3) + 8 * (reg >> 2);
                C[(size_t)row * N + col] = acc[m][n][reg] + bv;
            }
        }
    }
}

extern "C" void kernel_launch(void* const* d_in, const int* in_sizes, int n_in,
                              void* d_out, int out_size, void* d_ws, size_t ws_size,
                              hipStream_t stream) {
    const float* x = (const float*)d_in[0];     // [M,K]
    const float* w = (const float*)d_in[1];     // [N,K]
    const float* bias = (const float*)d_in[2];  // [N]
    float* out = (float*)d_out;

    const int N = in_sizes[2];                 // 16384
    const int K = in_sizes[1] / N;             // 4096
    const int M = in_sizes[0] / K;             // 8192

    unsigned char* xq = (unsigned char*)d_ws;          // M*K = 33.5 MB
    unsigned char* wq = xq + (size_t)M * K;            // N*K = 67 MB

    int nx8 = M * K / 8;
    int nw8 = N * K / 8;
    int ntot = nx8 + nw8;
    quant8_both<<<(ntot + 255) / 256, 256, 0, stream>>>(
        (const float4*)x, (int2*)xq, nx8,
        (const float4*)w, (int2*)wq, nw8);

    int nwg = (M / BM) * (N / BN);  // 64*64 = 4096, %8==0
    gemm_fp8<<<nwg, 512, 0, stream>>>(
        xq, wq, bias, out, M, N, K);
}